// Round 7
// baseline (298.801 us; speedup 1.0000x reference)
//
#include <hip/hip_runtime.h>
#include <cstddef>

#define NN 100000
#define NE 600000
#define HID 128

typedef _Float16 half8 __attribute__((ext_vector_type(8)));
typedef _Float16 half2v __attribute__((ext_vector_type(2)));
typedef float f32x4 __attribute__((ext_vector_type(4)));

union H8 { _Float16 h[8]; half2v p[4]; uint4 u; half8 v; };

// ---------------------------------------------------------------- degree (int)
__global__ void k_degi(const int* __restrict__ col, int* __restrict__ degi, int E) {
    int e = blockIdx.x * blockDim.x + threadIdx.x;
    if (e < E) atomicAdd(&degi[col[e]], 1);
}

// ---------------------------------------------------------------- W -> WT f16
__global__ void k_wprep(const float* __restrict__ W1, const float* __restrict__ W2,
                        const float* __restrict__ W3, _Float16* __restrict__ wt) {
    int b = blockIdx.x;            // 0..383
    int layer = b >> 7, k = b & 127;
    const float* W = layer == 0 ? W1 : (layer == 1 ? W2 : W3);
    int c = threadIdx.x;           // 0..127
    wt[((size_t)layer << 14) + c * 128 + k] = (_Float16)W[k * 128 + c];
}

// ---------------------------------------------------------------- prefix scan
__global__ void k_blocksum(const int* __restrict__ degi, float* __restrict__ dinv,
                           int* __restrict__ bsum, int N) {
    __shared__ int sh[256];
    int i = blockIdx.x * 256 + threadIdx.x;
    int v = i < N ? degi[i] : 0;
    if (i < N) dinv[i] = v > 0 ? rsqrtf((float)v) : 0.0f;
    sh[threadIdx.x] = v;
    __syncthreads();
    for (int s = 128; s > 0; s >>= 1) {
        if (threadIdx.x < s) sh[threadIdx.x] += sh[threadIdx.x + s];
        __syncthreads();
    }
    if (threadIdx.x == 0) bsum[blockIdx.x] = sh[0];
}

__global__ void k_scan_bsum(int* __restrict__ bsum, int nb) {
    __shared__ int sh[512];
    int tid = threadIdx.x;
    int v = (tid < nb) ? bsum[tid] : 0;
    sh[tid] = v;
    __syncthreads();
    #pragma unroll
    for (int s = 1; s < 512; s <<= 1) {
        int t = (tid >= s) ? sh[tid - s] : 0;
        __syncthreads();
        sh[tid] += t;
        __syncthreads();
    }
    if (tid < nb) bsum[tid] = sh[tid] - v;   // exclusive
}

__global__ void k_scan_apply(const int* __restrict__ degi, const int* __restrict__ bsum,
                             int* __restrict__ rowptr, int* __restrict__ cursor, int N) {
    __shared__ int sh[256];
    int i = blockIdx.x * 256 + threadIdx.x;
    int v = (i < N) ? degi[i] : 0;
    sh[threadIdx.x] = v;
    __syncthreads();
    #pragma unroll
    for (int s = 1; s < 256; s <<= 1) {
        int t = (threadIdx.x >= s) ? sh[threadIdx.x - s] : 0;
        __syncthreads();
        sh[threadIdx.x] += t;
        __syncthreads();
    }
    if (i < N) {
        int excl = bsum[blockIdx.x] + sh[threadIdx.x] - v;
        rowptr[i] = excl;
        cursor[i] = excl;
        if (i == N - 1) rowptr[N] = bsum[blockIdx.x] + sh[threadIdx.x];
    }
}

__global__ void k_fill_csr(const int* __restrict__ row, const int* __restrict__ col,
                           int* __restrict__ cursor, int* __restrict__ csr_src, int E) {
    int e = blockIdx.x * blockDim.x + threadIdx.x;
    if (e >= E) return;
    int r = row[e], c = col[e];
    int pos = atomicAdd(&cursor[c], 1);
    csr_src[pos] = r;
}

// ---------------------------------------------------------------- MFMA GEMM
// H[r] (f16) = dinv[r] * (A[r] @ W)   (A pre-activated by aggregate)
template <typename TA>
__global__ __launch_bounds__(256, 2) void k_gemm(
    const TA* __restrict__ A, const _Float16* __restrict__ WT,
    const float* __restrict__ dinv, _Float16* __restrict__ H, int nrows)
{
    __shared__ _Float16 asl[128 * 128];   // 32 KB
    __shared__ _Float16 wsl[128 * 128];   // 32 KB
    const int tid  = threadIdx.x;
    const int lane = tid & 63;
    const int w    = tid >> 6;
    const int wm   = w >> 1, wn = w & 1;
    const int ln15 = lane & 15;
    const int hi   = lane >> 4;           // 0..3
    const int row0 = blockIdx.x * 128;

    #pragma unroll
    for (int i = 0; i < 8; ++i) {
        int g = i * 256 + tid;
        int c = g >> 4, k8 = (g & 15) << 3;
        uint4 wv = *(const uint4*)(WT + c * 128 + k8);
        *(uint4*)&wsl[c * 128 + (k8 ^ ((c & 7) << 3))] = wv;
    }
    #pragma unroll
    for (int i = 0; i < 8; ++i) {
        int g = i * 256 + tid;
        int r = g >> 4, c8 = (g & 15) << 3;
        int gr = row0 + r; if (gr >= nrows) gr = nrows - 1;
        if constexpr (sizeof(TA) == 4) {
            const float4* src = (const float4*)(A + (size_t)gr * HID + c8);
            float4 v0 = src[0], v1 = src[1];
            H8 o;
            o.h[0] = (_Float16)v0.x; o.h[1] = (_Float16)v0.y;
            o.h[2] = (_Float16)v0.z; o.h[3] = (_Float16)v0.w;
            o.h[4] = (_Float16)v1.x; o.h[5] = (_Float16)v1.y;
            o.h[6] = (_Float16)v1.z; o.h[7] = (_Float16)v1.w;
            *(uint4*)&asl[r * 128 + (c8 ^ ((r & 7) << 3))] = o.u;
        } else {
            uint4 u = *(const uint4*)(A + (size_t)gr * HID + c8);
            *(uint4*)&asl[r * 128 + (c8 ^ ((r & 7) << 3))] = u;
        }
    }
    __syncthreads();

    f32x4 acc[4][4];
    #pragma unroll
    for (int i = 0; i < 4; ++i)
        #pragma unroll
        for (int j = 0; j < 4; ++j) {
            acc[i][j][0] = 0.0f; acc[i][j][1] = 0.0f;
            acc[i][j][2] = 0.0f; acc[i][j][3] = 0.0f;
        }

    #pragma unroll
    for (int ks = 0; ks < 4; ++ks) {
        const int k0 = ks * 32 + hi * 8;
        half8 a[4], b[4];
        #pragma unroll
        for (int i = 0; i < 4; ++i) {
            int ra = wm * 64 + i * 16 + ln15;
            a[i] = *(const half8*)&asl[ra * 128 + (k0 ^ ((ra & 7) << 3))];
            int cb = wn * 64 + i * 16 + ln15;
            b[i] = *(const half8*)&wsl[cb * 128 + (k0 ^ ((cb & 7) << 3))];
        }
        #pragma unroll
        for (int i = 0; i < 4; ++i)
            #pragma unroll
            for (int j = 0; j < 4; ++j)
                acc[i][j] = __builtin_amdgcn_mfma_f32_16x16x32_f16(a[i], b[j], acc[i][j], 0, 0, 0);
    }

    #pragma unroll
    for (int i = 0; i < 4; ++i) {
        #pragma unroll
        for (int q = 0; q < 4; ++q) {
            int r = row0 + wm * 64 + i * 16 + hi * 4 + q;
            if (r < nrows) {
                float s = dinv[r];
                #pragma unroll
                for (int j = 0; j < 4; ++j) {
                    H[(size_t)r * HID + wn * 64 + j * 16 + ln15] =
                        (_Float16)(acc[i][j][q] * s);
                }
            }
        }
    }
}

// ---------------------------------------------------------------- aggregate
// one WAVE per node; lane = fg*4 + es (es in LOW bits); round gathers 4 rows.
// Fold over es via shfl_xor(1),(2); then lane stores features f0=2*lane,2*lane+1
// -> consecutive lanes store consecutive addresses (full 64B sectors/quarter).
// MODE 0: a16[node] = relu(dinv*acc + bias)  (f16)
// MODE 1: out[node] = dinv*acc + bias        (f32)
template <int MODE>
__global__ __launch_bounds__(256) void k_aggregate(
    const _Float16* __restrict__ hs, const int* __restrict__ csr_src,
    const int* __restrict__ rowptr, const float* __restrict__ dinv,
    const float* __restrict__ bias, void* __restrict__ aggv, int N)
{
    int node = blockIdx.x * 4 + (threadIdx.x >> 6);
    if (node >= N) return;
    int lane = threadIdx.x & 63;
    int es   = lane & 3;            // edge slot (LOW bits)
    int fg   = lane >> 2;           // feature group: features fg*8 .. fg*8+7
    int beg = rowptr[node], end = rowptr[node + 1];

    float accf[8];
    #pragma unroll
    for (int j = 0; j < 8; ++j) accf[j] = 0.0f;

#if __has_builtin(__builtin_amdgcn_fdot2)
    const half2v selx = {(_Float16)1.0f, (_Float16)0.0f};
    const half2v sely = {(_Float16)0.0f, (_Float16)1.0f};
#define ACC8(hh)                                                              \
    do {                                                                      \
        _Pragma("unroll")                                                     \
        for (int p = 0; p < 4; ++p) {                                         \
            accf[2*p]   = __builtin_amdgcn_fdot2((hh).p[p], selx, accf[2*p],   false); \
            accf[2*p+1] = __builtin_amdgcn_fdot2((hh).p[p], sely, accf[2*p+1], false); \
        }                                                                     \
    } while (0)
#else
#define ACC8(hh)                                                              \
    do {                                                                      \
        _Pragma("unroll")                                                     \
        for (int j = 0; j < 8; ++j) accf[j] += (float)(hh).h[j];              \
    } while (0)
#endif

    const uint4 z = make_uint4(0, 0, 0, 0);
    int nr = (end - beg + 3) >> 2;      // wave-uniform round count
    int e  = beg + es;
    int r  = 0;
    for (; r + 1 < nr; r += 2, e += 8) {
        int s0 = (e     < end) ? csr_src[e]     : -1;
        int s1 = (e + 4 < end) ? csr_src[e + 4] : -1;
        uint4 u0 = (s0 >= 0) ? *(const uint4*)(hs + (size_t)s0 * HID + fg * 8) : z;
        uint4 u1 = (s1 >= 0) ? *(const uint4*)(hs + (size_t)s1 * HID + fg * 8) : z;
        H8 h0; h0.u = u0;
        H8 h1; h1.u = u1;
        ACC8(h0);
        ACC8(h1);
    }
    if (r < nr) {
        int s0 = (e < end) ? csr_src[e] : -1;
        uint4 u0 = (s0 >= 0) ? *(const uint4*)(hs + (size_t)s0 * HID + fg * 8) : z;
        H8 h0; h0.u = u0;
        ACC8(h0);
    }
#undef ACC8

    // fold the 4 edge slots (low lane bits) — every lane gets the full fg sums
    #pragma unroll
    for (int j = 0; j < 8; ++j) {
        accf[j] += __shfl_xor(accf[j], 1);
        accf[j] += __shfl_xor(accf[j], 2);
    }

    // lane owns features f0 = 2*lane, 2*lane+1  (= fg*8 + es*2)
    float v0 = (es == 0) ? accf[0] : (es == 1) ? accf[2] : (es == 2) ? accf[4] : accf[6];
    float v1 = (es == 0) ? accf[1] : (es == 1) ? accf[3] : (es == 2) ? accf[5] : accf[7];
    int f0 = lane * 2;
    float s = dinv[node];
    float2 bv = *(const float2*)(bias + f0);
    v0 = v0 * s + bv.x;
    v1 = v1 * s + bv.y;
    if constexpr (MODE == 0) {
        union { _Float16 h[2]; unsigned u; } o;
        o.h[0] = (_Float16)fmaxf(v0, 0.0f);
        o.h[1] = (_Float16)fmaxf(v1, 0.0f);
        *(unsigned*)((_Float16*)aggv + (size_t)node * HID + f0) = o.u;
    } else {
        *(float2*)((float*)aggv + (size_t)node * HID + f0) = make_float2(v0, v1);
    }
}

// ---------------------------------------------------------------- launch
extern "C" void kernel_launch(void* const* d_in, const int* in_sizes, int n_in,
                              void* d_out, int out_size, void* d_ws, size_t ws_size,
                              hipStream_t stream)
{
    const float* x  = (const float*)d_in[0];
    const float* W1 = (const float*)d_in[1];
    const float* b1 = (const float*)d_in[2];
    const float* W2 = (const float*)d_in[3];
    const float* b2 = (const float*)d_in[4];
    const float* W3 = (const float*)d_in[5];
    const float* b3 = (const float*)d_in[6];
    const int*   ei = (const int*)d_in[7];
    const int* row  = ei;            // sources
    const int* colv = ei + NE;       // targets
    float* out = (float*)d_out;

    _Float16* h16 = (_Float16*)d_ws;                  // NN*HID
    _Float16* a16 = h16 + (size_t)NN * HID;           // NN*HID
    _Float16* wt  = a16 + (size_t)NN * HID;           // 3*128*128
    int*   degi    = (int*)(wt + 3 * 128 * 128);      // NN
    float* dinv    = (float*)(degi + NN);             // NN
    int*   rowptr  = (int*)(dinv + NN);               // NN+1
    int*   cursor  = rowptr + NN + 1;                 // NN
    int*   bsum    = cursor + NN;                     // 512
    int*   csr_src = bsum + 512;                      // NE

    const int TB = 256;
    const int nScanBlocks = (NN + 255) / 256;         // 391

    k_wprep<<<384, 128, 0, stream>>>(W1, W2, W3, wt);
    hipMemsetAsync(degi, 0, NN * sizeof(int), stream);
    k_degi      <<<(NE + TB - 1) / TB, TB, 0, stream>>>(colv, degi, NE);
    k_blocksum  <<<nScanBlocks, 256, 0, stream>>>(degi, dinv, bsum, NN);
    k_scan_bsum <<<1, 512, 0, stream>>>(bsum, nScanBlocks);
    k_scan_apply<<<nScanBlocks, 256, 0, stream>>>(degi, bsum, rowptr, cursor, NN);
    k_fill_csr  <<<(NE + TB - 1) / TB, TB, 0, stream>>>(row, colv, cursor, csr_src, NE);

    const int gemmBlocks = (NN + 127) / 128;          // 782
    const int aggBlocks  = (NN + 3) / 4;              // 25000

    // layer 1: h16 = dinv*(x@W1) ; a16 = relu(agg(h16)+b1)
    k_gemm<float><<<gemmBlocks, TB, 0, stream>>>(x, wt, dinv, h16, NN);
    k_aggregate<0><<<aggBlocks, TB, 0, stream>>>(h16, csr_src, rowptr, dinv, b1, a16, NN);
    // layer 2: h16 = dinv*(a16@W2) ; a16 = relu(agg(h16)+b2)
    k_gemm<_Float16><<<gemmBlocks, TB, 0, stream>>>(a16, wt + (1 << 14), dinv, h16, NN);
    k_aggregate<0><<<aggBlocks, TB, 0, stream>>>(h16, csr_src, rowptr, dinv, b2, a16, NN);
    // layer 3: h16 = dinv*(a16@W3) ; out = agg(h16) + b3
    k_gemm<_Float16><<<gemmBlocks, TB, 0, stream>>>(a16, wt + (2 << 14), dinv, h16, NN);
    k_aggregate<1><<<aggBlocks, TB, 0, stream>>>(h16, csr_src, rowptr, dinv, b3, out, NN);
}

// Round 8
// 253.748 us; speedup vs baseline: 1.1776x; 1.1776x over previous
//
#include <hip/hip_runtime.h>
#include <cstddef>

#define NN 100000
#define NE 600000
#define HID 128

typedef _Float16 half8 __attribute__((ext_vector_type(8)));
typedef _Float16 half2v __attribute__((ext_vector_type(2)));
typedef float f32x4 __attribute__((ext_vector_type(4)));

union H8 { _Float16 h[8]; half2v p[4]; uint4 u; half8 v; };

// ---------------------------------------------------------------- degree (int)
__global__ void k_degi(const int* __restrict__ col, int* __restrict__ degi, int E) {
    int e = blockIdx.x * blockDim.x + threadIdx.x;
    if (e < E) atomicAdd(&degi[col[e]], 1);
}

// ---------------------------------------------------------------- W -> WT f16
__global__ void k_wprep(const float* __restrict__ W1, const float* __restrict__ W2,
                        const float* __restrict__ W3, _Float16* __restrict__ wt) {
    int b = blockIdx.x;            // 0..383
    int layer = b >> 7, k = b & 127;
    const float* W = layer == 0 ? W1 : (layer == 1 ? W2 : W3);
    int c = threadIdx.x;           // 0..127
    wt[((size_t)layer << 14) + c * 128 + k] = (_Float16)W[k * 128 + c];
}

// ---------------------------------------------------------------- prefix scan
__global__ void k_blocksum(const int* __restrict__ degi, float* __restrict__ dinv,
                           int* __restrict__ bsum, int N) {
    __shared__ int sh[256];
    int i = blockIdx.x * 256 + threadIdx.x;
    int v = i < N ? degi[i] : 0;
    if (i < N) dinv[i] = v > 0 ? rsqrtf((float)v) : 0.0f;
    sh[threadIdx.x] = v;
    __syncthreads();
    for (int s = 128; s > 0; s >>= 1) {
        if (threadIdx.x < s) sh[threadIdx.x] += sh[threadIdx.x + s];
        __syncthreads();
    }
    if (threadIdx.x == 0) bsum[blockIdx.x] = sh[0];
}

__global__ void k_scan_bsum(int* __restrict__ bsum, int nb) {
    __shared__ int sh[512];
    int tid = threadIdx.x;
    int v = (tid < nb) ? bsum[tid] : 0;
    sh[tid] = v;
    __syncthreads();
    #pragma unroll
    for (int s = 1; s < 512; s <<= 1) {
        int t = (tid >= s) ? sh[tid - s] : 0;
        __syncthreads();
        sh[tid] += t;
        __syncthreads();
    }
    if (tid < nb) bsum[tid] = sh[tid] - v;   // exclusive
}

__global__ void k_scan_apply(const int* __restrict__ degi, const int* __restrict__ bsum,
                             int* __restrict__ rowptr, int* __restrict__ cursor, int N) {
    __shared__ int sh[256];
    int i = blockIdx.x * 256 + threadIdx.x;
    int v = (i < N) ? degi[i] : 0;
    sh[threadIdx.x] = v;
    __syncthreads();
    #pragma unroll
    for (int s = 1; s < 256; s <<= 1) {
        int t = (threadIdx.x >= s) ? sh[threadIdx.x - s] : 0;
        __syncthreads();
        sh[threadIdx.x] += t;
        __syncthreads();
    }
    if (i < N) {
        int excl = bsum[blockIdx.x] + sh[threadIdx.x] - v;
        rowptr[i] = excl;
        cursor[i] = excl;
        if (i == N - 1) rowptr[N] = bsum[blockIdx.x] + sh[threadIdx.x];
    }
}

// csr_off stores BYTE offset of the source row (src * HID * 2, fits int32)
__global__ void k_fill_csr(const int* __restrict__ row, const int* __restrict__ col,
                           int* __restrict__ cursor, int* __restrict__ csr_off, int E) {
    int e = blockIdx.x * blockDim.x + threadIdx.x;
    if (e >= E) return;
    int r = row[e], c = col[e];
    int pos = atomicAdd(&cursor[c], 1);
    csr_off[pos] = r * (HID * 2);
}

// ---------------------------------------------------------------- MFMA GEMM
// H[r] (f16) = dinv[r] * (A[r] @ W)   (A pre-activated by aggregate)
template <typename TA>
__global__ __launch_bounds__(256, 2) void k_gemm(
    const TA* __restrict__ A, const _Float16* __restrict__ WT,
    const float* __restrict__ dinv, _Float16* __restrict__ H, int nrows)
{
    __shared__ _Float16 asl[128 * 128];   // 32 KB
    __shared__ _Float16 wsl[128 * 128];   // 32 KB
    const int tid  = threadIdx.x;
    const int lane = tid & 63;
    const int w    = tid >> 6;
    const int wm   = w >> 1, wn = w & 1;
    const int ln15 = lane & 15;
    const int hi   = lane >> 4;           // 0..3
    const int row0 = blockIdx.x * 128;

    #pragma unroll
    for (int i = 0; i < 8; ++i) {
        int g = i * 256 + tid;
        int c = g >> 4, k8 = (g & 15) << 3;
        uint4 wv = *(const uint4*)(WT + c * 128 + k8);
        *(uint4*)&wsl[c * 128 + (k8 ^ ((c & 7) << 3))] = wv;
    }
    #pragma unroll
    for (int i = 0; i < 8; ++i) {
        int g = i * 256 + tid;
        int r = g >> 4, c8 = (g & 15) << 3;
        int gr = row0 + r; if (gr >= nrows) gr = nrows - 1;
        if constexpr (sizeof(TA) == 4) {
            const float4* src = (const float4*)(A + (size_t)gr * HID + c8);
            float4 v0 = src[0], v1 = src[1];
            H8 o;
            o.h[0] = (_Float16)v0.x; o.h[1] = (_Float16)v0.y;
            o.h[2] = (_Float16)v0.z; o.h[3] = (_Float16)v0.w;
            o.h[4] = (_Float16)v1.x; o.h[5] = (_Float16)v1.y;
            o.h[6] = (_Float16)v1.z; o.h[7] = (_Float16)v1.w;
            *(uint4*)&asl[r * 128 + (c8 ^ ((r & 7) << 3))] = o.u;
        } else {
            uint4 u = *(const uint4*)(A + (size_t)gr * HID + c8);
            *(uint4*)&asl[r * 128 + (c8 ^ ((r & 7) << 3))] = u;
        }
    }
    __syncthreads();

    f32x4 acc[4][4];
    #pragma unroll
    for (int i = 0; i < 4; ++i)
        #pragma unroll
        for (int j = 0; j < 4; ++j) {
            acc[i][j][0] = 0.0f; acc[i][j][1] = 0.0f;
            acc[i][j][2] = 0.0f; acc[i][j][3] = 0.0f;
        }

    #pragma unroll
    for (int ks = 0; ks < 4; ++ks) {
        const int k0 = ks * 32 + hi * 8;
        half8 a[4], b[4];
        #pragma unroll
        for (int i = 0; i < 4; ++i) {
            int ra = wm * 64 + i * 16 + ln15;
            a[i] = *(const half8*)&asl[ra * 128 + (k0 ^ ((ra & 7) << 3))];
            int cb = wn * 64 + i * 16 + ln15;
            b[i] = *(const half8*)&wsl[cb * 128 + (k0 ^ ((cb & 7) << 3))];
        }
        #pragma unroll
        for (int i = 0; i < 4; ++i)
            #pragma unroll
            for (int j = 0; j < 4; ++j)
                acc[i][j] = __builtin_amdgcn_mfma_f32_16x16x32_f16(a[i], b[j], acc[i][j], 0, 0, 0);
    }

    #pragma unroll
    for (int i = 0; i < 4; ++i) {
        #pragma unroll
        for (int q = 0; q < 4; ++q) {
            int r = row0 + wm * 64 + i * 16 + hi * 4 + q;
            if (r < nrows) {
                float s = dinv[r];
                #pragma unroll
                for (int j = 0; j < 4; ++j) {
                    H[(size_t)r * HID + wn * 64 + j * 16 + ln15] =
                        (_Float16)(acc[i][j][q] * s);
                }
            }
        }
    }
}

// ---------------------------------------------------------------- aggregate
// one WAVE per node; lane = es*16 + fg (es HIGH bits -> quarter-wave reads one
// contiguous 256B row). Fold es via shfl_xor(16),(32). Lane (es,fg) stores
// feature pair f0 = fg*8 + es*2.
// MODE 0: a16[node] = relu(dinv*acc + bias)  (f16)
// MODE 1: out[node] = dinv*acc + bias        (f32)
template <int MODE>
__global__ __launch_bounds__(256) void k_aggregate(
    const _Float16* __restrict__ hs, const int* __restrict__ csr_off,
    const int* __restrict__ rowptr, const float* __restrict__ dinv,
    const float* __restrict__ bias, void* __restrict__ aggv, int N)
{
    int node = blockIdx.x * 4 + (threadIdx.x >> 6);
    if (node >= N) return;
    int lane = threadIdx.x & 63;
    int es   = lane >> 4;           // 0..3  edge slot (HIGH bits)
    int fg   = lane & 15;           // feature group: features fg*8 .. fg*8+7
    int beg = rowptr[node], end = rowptr[node + 1];

    float accf[8];
    #pragma unroll
    for (int j = 0; j < 8; ++j) accf[j] = 0.0f;

#if __has_builtin(__builtin_amdgcn_fdot2)
    const half2v selx = {(_Float16)1.0f, (_Float16)0.0f};
    const half2v sely = {(_Float16)0.0f, (_Float16)1.0f};
#define ACC8(hh)                                                              \
    do {                                                                      \
        _Pragma("unroll")                                                     \
        for (int p = 0; p < 4; ++p) {                                         \
            accf[2*p]   = __builtin_amdgcn_fdot2((hh).p[p], selx, accf[2*p],   false); \
            accf[2*p+1] = __builtin_amdgcn_fdot2((hh).p[p], sely, accf[2*p+1], false); \
        }                                                                     \
    } while (0)
#else
#define ACC8(hh)                                                              \
    do {                                                                      \
        _Pragma("unroll")                                                     \
        for (int j = 0; j < 8; ++j) accf[j] += (float)(hh).h[j];              \
    } while (0)
#endif

    const uint4 z = make_uint4(0, 0, 0, 0);
    const char* hb = (const char*)hs;
    int nr = (end - beg + 3) >> 2;      // wave-uniform round count
    int e  = beg + es;
    int r  = 0;
    for (; r + 1 < nr; r += 2, e += 8) {
        int o0 = (e     < end) ? csr_off[e]     : -1;
        int o1 = (e + 4 < end) ? csr_off[e + 4] : -1;
        uint4 u0 = (o0 >= 0) ? *(const uint4*)(hb + (size_t)(unsigned)o0 + fg * 16) : z;
        uint4 u1 = (o1 >= 0) ? *(const uint4*)(hb + (size_t)(unsigned)o1 + fg * 16) : z;
        H8 h0; h0.u = u0;
        H8 h1; h1.u = u1;
        ACC8(h0);
        ACC8(h1);
    }
    if (r < nr) {
        int o0 = (e < end) ? csr_off[e] : -1;
        uint4 u0 = (o0 >= 0) ? *(const uint4*)(hb + (size_t)(unsigned)o0 + fg * 16) : z;
        H8 h0; h0.u = u0;
        ACC8(h0);
    }
#undef ACC8

    // fold the 4 edge slots — butterfly leaves full sum in EVERY lane
    #pragma unroll
    for (int j = 0; j < 8; ++j) {
        accf[j] += __shfl_xor(accf[j], 16);
        accf[j] += __shfl_xor(accf[j], 32);
    }

    // lane (es,fg) owns features f0, f0+1 (static ?: select — no dyn indexing)
    float v0 = es < 2 ? (es == 0 ? accf[0] : accf[2])
                      : (es == 2 ? accf[4] : accf[6]);
    float v1 = es < 2 ? (es == 0 ? accf[1] : accf[3])
                      : (es == 2 ? accf[5] : accf[7]);
    int f0 = fg * 8 + es * 2;
    float s = dinv[node];
    float2 bv = *(const float2*)(bias + f0);
    v0 = v0 * s + bv.x;
    v1 = v1 * s + bv.y;
    if constexpr (MODE == 0) {
        union { _Float16 h[2]; unsigned u; } o;
        o.h[0] = (_Float16)fmaxf(v0, 0.0f);
        o.h[1] = (_Float16)fmaxf(v1, 0.0f);
        *(unsigned*)((_Float16*)aggv + (size_t)node * HID + f0) = o.u;
    } else {
        *(float2*)((float*)aggv + (size_t)node * HID + f0) = make_float2(v0, v1);
    }
}

// ---------------------------------------------------------------- launch
extern "C" void kernel_launch(void* const* d_in, const int* in_sizes, int n_in,
                              void* d_out, int out_size, void* d_ws, size_t ws_size,
                              hipStream_t stream)
{
    const float* x  = (const float*)d_in[0];
    const float* W1 = (const float*)d_in[1];
    const float* b1 = (const float*)d_in[2];
    const float* W2 = (const float*)d_in[3];
    const float* b2 = (const float*)d_in[4];
    const float* W3 = (const float*)d_in[5];
    const float* b3 = (const float*)d_in[6];
    const int*   ei = (const int*)d_in[7];
    const int* row  = ei;            // sources
    const int* colv = ei + NE;       // targets
    float* out = (float*)d_out;

    _Float16* h16 = (_Float16*)d_ws;                  // NN*HID
    _Float16* a16 = h16 + (size_t)NN * HID;           // NN*HID
    _Float16* wt  = a16 + (size_t)NN * HID;           // 3*128*128
    int*   degi    = (int*)(wt + 3 * 128 * 128);      // NN
    float* dinv    = (float*)(degi + NN);             // NN
    int*   rowptr  = (int*)(dinv + NN);               // NN+1
    int*   cursor  = rowptr + NN + 1;                 // NN
    int*   bsum    = cursor + NN;                     // 512
    int*   csr_off = bsum + 512;                      // NE

    const int TB = 256;
    const int nScanBlocks = (NN + 255) / 256;         // 391

    k_wprep<<<384, 128, 0, stream>>>(W1, W2, W3, wt);
    hipMemsetAsync(degi, 0, NN * sizeof(int), stream);
    k_degi      <<<(NE + TB - 1) / TB, TB, 0, stream>>>(colv, degi, NE);
    k_blocksum  <<<nScanBlocks, 256, 0, stream>>>(degi, dinv, bsum, NN);
    k_scan_bsum <<<1, 512, 0, stream>>>(bsum, nScanBlocks);
    k_scan_apply<<<nScanBlocks, 256, 0, stream>>>(degi, bsum, rowptr, cursor, NN);
    k_fill_csr  <<<(NE + TB - 1) / TB, TB, 0, stream>>>(row, colv, cursor, csr_off, NE);

    const int gemmBlocks = (NN + 127) / 128;          // 782
    const int aggBlocks  = (NN + 3) / 4;              // 25000

    // layer 1: h16 = dinv*(x@W1) ; a16 = relu(agg(h16)+b1)
    k_gemm<float><<<gemmBlocks, TB, 0, stream>>>(x, wt, dinv, h16, NN);
    k_aggregate<0><<<aggBlocks, TB, 0, stream>>>(h16, csr_off, rowptr, dinv, b1, a16, NN);
    // layer 2: h16 = dinv*(a16@W2) ; a16 = relu(agg(h16)+b2)
    k_gemm<_Float16><<<gemmBlocks, TB, 0, stream>>>(a16, wt + (1 << 14), dinv, h16, NN);
    k_aggregate<0><<<aggBlocks, TB, 0, stream>>>(h16, csr_off, rowptr, dinv, b2, a16, NN);
    // layer 3: h16 = dinv*(a16@W3) ; out = agg(h16) + b3
    k_gemm<_Float16><<<gemmBlocks, TB, 0, stream>>>(a16, wt + (2 << 14), dinv, h16, NN);
    k_aggregate<1><<<aggBlocks, TB, 0, stream>>>(h16, csr_off, rowptr, dinv, b3, out, NN);
}

// Round 9
// 247.895 us; speedup vs baseline: 1.2054x; 1.0236x over previous
//
#include <hip/hip_runtime.h>
#include <cstddef>

#define NN 100000
#define NE 600000
#define HID 128

typedef _Float16 half8 __attribute__((ext_vector_type(8)));
typedef _Float16 half2v __attribute__((ext_vector_type(2)));
typedef float f32x4 __attribute__((ext_vector_type(4)));

union H8 { _Float16 h[8]; half2v p[4]; uint4 u; half8 v; };

// ---------------------------------------------------------------- degree (int)
__global__ void k_degi(const int* __restrict__ col, int* __restrict__ degi, int E) {
    int e = blockIdx.x * blockDim.x + threadIdx.x;
    if (e < E) atomicAdd(&degi[col[e]], 1);
}

// ---------------------------------------------------------------- W -> WT f16
__global__ void k_wprep(const float* __restrict__ W1, const float* __restrict__ W2,
                        const float* __restrict__ W3, _Float16* __restrict__ wt) {
    int b = blockIdx.x;            // 0..383
    int layer = b >> 7, k = b & 127;
    const float* W = layer == 0 ? W1 : (layer == 1 ? W2 : W3);
    int c = threadIdx.x;           // 0..127
    wt[((size_t)layer << 14) + c * 128 + k] = (_Float16)W[k * 128 + c];
}

// ---------------------------------------------------------------- prefix scan
__global__ void k_blocksum(const int* __restrict__ degi, float* __restrict__ dinv,
                           int* __restrict__ bsum, int N) {
    __shared__ int sh[256];
    int i = blockIdx.x * 256 + threadIdx.x;
    int v = i < N ? degi[i] : 0;
    if (i < N) dinv[i] = v > 0 ? rsqrtf((float)v) : 0.0f;
    sh[threadIdx.x] = v;
    __syncthreads();
    for (int s = 128; s > 0; s >>= 1) {
        if (threadIdx.x < s) sh[threadIdx.x] += sh[threadIdx.x + s];
        __syncthreads();
    }
    if (threadIdx.x == 0) bsum[blockIdx.x] = sh[0];
}

__global__ void k_scan_bsum(int* __restrict__ bsum, int nb) {
    __shared__ int sh[512];
    int tid = threadIdx.x;
    int v = (tid < nb) ? bsum[tid] : 0;
    sh[tid] = v;
    __syncthreads();
    #pragma unroll
    for (int s = 1; s < 512; s <<= 1) {
        int t = (tid >= s) ? sh[tid - s] : 0;
        __syncthreads();
        sh[tid] += t;
        __syncthreads();
    }
    if (tid < nb) bsum[tid] = sh[tid] - v;   // exclusive
}

__global__ void k_scan_apply(const int* __restrict__ degi, const int* __restrict__ bsum,
                             int* __restrict__ rowptr, int* __restrict__ cursor, int N) {
    __shared__ int sh[256];
    int i = blockIdx.x * 256 + threadIdx.x;
    int v = (i < N) ? degi[i] : 0;
    sh[threadIdx.x] = v;
    __syncthreads();
    #pragma unroll
    for (int s = 1; s < 256; s <<= 1) {
        int t = (threadIdx.x >= s) ? sh[threadIdx.x - s] : 0;
        __syncthreads();
        sh[threadIdx.x] += t;
        __syncthreads();
    }
    if (i < N) {
        int excl = bsum[blockIdx.x] + sh[threadIdx.x] - v;
        rowptr[i] = excl;
        cursor[i] = excl;
        if (i == N - 1) rowptr[N] = bsum[blockIdx.x] + sh[threadIdx.x];
    }
}

// csr_off stores BYTE offset of the source row (src * HID * 2, fits int32)
__global__ void k_fill_csr(const int* __restrict__ row, const int* __restrict__ col,
                           int* __restrict__ cursor, int* __restrict__ csr_off, int E) {
    int e = blockIdx.x * blockDim.x + threadIdx.x;
    if (e >= E) return;
    int r = row[e], c = col[e];
    int pos = atomicAdd(&cursor[c], 1);
    csr_off[pos] = r * (HID * 2);
}

// ---------------------------------------------------------------- MFMA GEMM
// H[r] (f16) = dinv[r] * (A[r] @ W)   (A pre-activated by aggregate)
template <typename TA>
__global__ __launch_bounds__(256, 2) void k_gemm(
    const TA* __restrict__ A, const _Float16* __restrict__ WT,
    const float* __restrict__ dinv, _Float16* __restrict__ H, int nrows)
{
    __shared__ _Float16 asl[128 * 128];   // 32 KB
    __shared__ _Float16 wsl[128 * 128];   // 32 KB
    const int tid  = threadIdx.x;
    const int lane = tid & 63;
    const int w    = tid >> 6;
    const int wm   = w >> 1, wn = w & 1;
    const int ln15 = lane & 15;
    const int hi   = lane >> 4;           // 0..3
    const int row0 = blockIdx.x * 128;

    #pragma unroll
    for (int i = 0; i < 8; ++i) {
        int g = i * 256 + tid;
        int c = g >> 4, k8 = (g & 15) << 3;
        uint4 wv = *(const uint4*)(WT + c * 128 + k8);
        *(uint4*)&wsl[c * 128 + (k8 ^ ((c & 7) << 3))] = wv;
    }
    #pragma unroll
    for (int i = 0; i < 8; ++i) {
        int g = i * 256 + tid;
        int r = g >> 4, c8 = (g & 15) << 3;
        int gr = row0 + r; if (gr >= nrows) gr = nrows - 1;
        if constexpr (sizeof(TA) == 4) {
            const float4* src = (const float4*)(A + (size_t)gr * HID + c8);
            float4 v0 = src[0], v1 = src[1];
            H8 o;
            o.h[0] = (_Float16)v0.x; o.h[1] = (_Float16)v0.y;
            o.h[2] = (_Float16)v0.z; o.h[3] = (_Float16)v0.w;
            o.h[4] = (_Float16)v1.x; o.h[5] = (_Float16)v1.y;
            o.h[6] = (_Float16)v1.z; o.h[7] = (_Float16)v1.w;
            *(uint4*)&asl[r * 128 + (c8 ^ ((r & 7) << 3))] = o.u;
        } else {
            uint4 u = *(const uint4*)(A + (size_t)gr * HID + c8);
            *(uint4*)&asl[r * 128 + (c8 ^ ((r & 7) << 3))] = u;
        }
    }
    __syncthreads();

    f32x4 acc[4][4];
    #pragma unroll
    for (int i = 0; i < 4; ++i)
        #pragma unroll
        for (int j = 0; j < 4; ++j) {
            acc[i][j][0] = 0.0f; acc[i][j][1] = 0.0f;
            acc[i][j][2] = 0.0f; acc[i][j][3] = 0.0f;
        }

    #pragma unroll
    for (int ks = 0; ks < 4; ++ks) {
        const int k0 = ks * 32 + hi * 8;
        half8 a[4], b[4];
        #pragma unroll
        for (int i = 0; i < 4; ++i) {
            int ra = wm * 64 + i * 16 + ln15;
            a[i] = *(const half8*)&asl[ra * 128 + (k0 ^ ((ra & 7) << 3))];
            int cb = wn * 64 + i * 16 + ln15;
            b[i] = *(const half8*)&wsl[cb * 128 + (k0 ^ ((cb & 7) << 3))];
        }
        #pragma unroll
        for (int i = 0; i < 4; ++i)
            #pragma unroll
            for (int j = 0; j < 4; ++j)
                acc[i][j] = __builtin_amdgcn_mfma_f32_16x16x32_f16(a[i], b[j], acc[i][j], 0, 0, 0);
    }

    #pragma unroll
    for (int i = 0; i < 4; ++i) {
        #pragma unroll
        for (int q = 0; q < 4; ++q) {
            int r = row0 + wm * 64 + i * 16 + hi * 4 + q;
            if (r < nrows) {
                float s = dinv[r];
                #pragma unroll
                for (int j = 0; j < 4; ++j) {
                    H[(size_t)r * HID + wn * 64 + j * 16 + ln15] =
                        (_Float16)(acc[i][j][q] * s);
                }
            }
        }
    }
}

// ---------------------------------------------------------------- aggregate
// block = 256 thr = 4 waves, handles 32 nodes. rowptr[33] + the block's whole
// contiguous csr_off range staged in LDS (coalesced) -> per-edge critical path
// is {LDS offset read -> gather} only. Wave w processes nodes w*8..w*8+7
// back-to-back (no barriers) so gathers overlap across nodes.
// lane = es*16 + fg (quarter-wave reads one contiguous 256B row).
// MODE 0: a16[node] = relu(dinv*acc + bias)  (f16)
// MODE 1: out[node] = dinv*acc + bias        (f32)
template <int MODE>
__global__ __launch_bounds__(256) void k_aggregate(
    const _Float16* __restrict__ hs, const int* __restrict__ csr_off,
    const int* __restrict__ rowptr, const float* __restrict__ dinv,
    const float* __restrict__ bias, void* __restrict__ aggv, int N)
{
    constexpr int NB = 32;
    constexpr int CAP = 2048;
    __shared__ int s_off[CAP + 8];     // +8 pad: masked-lane reads stay in bounds
    __shared__ int s_ptr[NB + 1];

    const int tid = threadIdx.x;
    const int n0  = blockIdx.x * NB;   // 3125 * 32 == 100000 exactly
    if (tid <= NB) s_ptr[tid] = rowptr[n0 + tid];
    __syncthreads();
    const int Rbeg = s_ptr[0];
    const int cnt  = s_ptr[NB] - Rbeg;
    const bool fast = cnt <= CAP;
    if (fast) {
        for (int i = tid; i < cnt; i += 256) s_off[i] = csr_off[Rbeg + i];
    }
    __syncthreads();
    const int* offp = fast ? (const int*)s_off : (csr_off + Rbeg);

    const int lane = tid & 63;
    const int w    = tid >> 6;
    const int es   = lane >> 4;        // 0..3  edge slot (HIGH bits)
    const int fg   = lane & 15;        // feature group
    const char* hb = (const char*)hs;
    const int f0   = fg * 8 + es * 2;
    const float2 bv = *(const float2*)(bias + f0);

#if __has_builtin(__builtin_amdgcn_fdot2)
    const half2v selx = {(_Float16)1.0f, (_Float16)0.0f};
    const half2v sely = {(_Float16)0.0f, (_Float16)1.0f};
#define ACC8(hh)                                                              \
    do {                                                                      \
        _Pragma("unroll")                                                     \
        for (int p = 0; p < 4; ++p) {                                         \
            accf[2*p]   = __builtin_amdgcn_fdot2((hh).p[p], selx, accf[2*p],   false); \
            accf[2*p+1] = __builtin_amdgcn_fdot2((hh).p[p], sely, accf[2*p+1], false); \
        }                                                                     \
    } while (0)
#else
#define ACC8(hh)                                                              \
    do {                                                                      \
        _Pragma("unroll")                                                     \
        for (int j = 0; j < 8; ++j) accf[j] += (float)(hh).h[j];              \
    } while (0)
#endif

    #pragma unroll 2
    for (int t = 0; t < 8; ++t) {
        const int ni   = (w << 3) + t;
        const int node = n0 + ni;
        const int beg  = s_ptr[ni] - Rbeg;
        const int end  = s_ptr[ni + 1] - Rbeg;

        float accf[8];
        #pragma unroll
        for (int j = 0; j < 8; ++j) accf[j] = 0.0f;

        const uint4 z = make_uint4(0, 0, 0, 0);
        int nr  = (end - beg + 3) >> 2;
        int idx = beg + es;
        int r   = 0;
        for (; r + 1 < nr; r += 2, idx += 8) {
            int o0 = (idx     < end) ? offp[idx]     : -1;
            int o1 = (idx + 4 < end) ? offp[idx + 4] : -1;
            uint4 u0 = (o0 >= 0) ? *(const uint4*)(hb + (size_t)(unsigned)o0 + fg * 16) : z;
            uint4 u1 = (o1 >= 0) ? *(const uint4*)(hb + (size_t)(unsigned)o1 + fg * 16) : z;
            H8 h0; h0.u = u0;
            H8 h1; h1.u = u1;
            ACC8(h0);
            ACC8(h1);
        }
        if (r < nr) {
            int o0 = (idx < end) ? offp[idx] : -1;
            uint4 u0 = (o0 >= 0) ? *(const uint4*)(hb + (size_t)(unsigned)o0 + fg * 16) : z;
            H8 h0; h0.u = u0;
            ACC8(h0);
        }

        // fold the 4 edge slots — butterfly leaves full sum in EVERY lane
        #pragma unroll
        for (int j = 0; j < 8; ++j) {
            accf[j] += __shfl_xor(accf[j], 16);
            accf[j] += __shfl_xor(accf[j], 32);
        }

        float v0 = es < 2 ? (es == 0 ? accf[0] : accf[2])
                          : (es == 2 ? accf[4] : accf[6]);
        float v1 = es < 2 ? (es == 0 ? accf[1] : accf[3])
                          : (es == 2 ? accf[5] : accf[7]);
        float s = dinv[node];
        v0 = v0 * s + bv.x;
        v1 = v1 * s + bv.y;
        if constexpr (MODE == 0) {
            union { _Float16 h[2]; unsigned u; } o;
            o.h[0] = (_Float16)fmaxf(v0, 0.0f);
            o.h[1] = (_Float16)fmaxf(v1, 0.0f);
            *(unsigned*)((_Float16*)aggv + (size_t)node * HID + f0) = o.u;
        } else {
            *(float2*)((float*)aggv + (size_t)node * HID + f0) = make_float2(v0, v1);
        }
    }
#undef ACC8
}

// ---------------------------------------------------------------- launch
extern "C" void kernel_launch(void* const* d_in, const int* in_sizes, int n_in,
                              void* d_out, int out_size, void* d_ws, size_t ws_size,
                              hipStream_t stream)
{
    const float* x  = (const float*)d_in[0];
    const float* W1 = (const float*)d_in[1];
    const float* b1 = (const float*)d_in[2];
    const float* W2 = (const float*)d_in[3];
    const float* b2 = (const float*)d_in[4];
    const float* W3 = (const float*)d_in[5];
    const float* b3 = (const float*)d_in[6];
    const int*   ei = (const int*)d_in[7];
    const int* row  = ei;            // sources
    const int* colv = ei + NE;       // targets
    float* out = (float*)d_out;

    _Float16* h16 = (_Float16*)d_ws;                  // NN*HID
    _Float16* a16 = h16 + (size_t)NN * HID;           // NN*HID
    _Float16* wt  = a16 + (size_t)NN * HID;           // 3*128*128
    int*   degi    = (int*)(wt + 3 * 128 * 128);      // NN
    float* dinv    = (float*)(degi + NN);             // NN
    int*   rowptr  = (int*)(dinv + NN);               // NN+1
    int*   cursor  = rowptr + NN + 1;                 // NN
    int*   bsum    = cursor + NN;                     // 512
    int*   csr_off = bsum + 512;                      // NE

    const int TB = 256;
    const int nScanBlocks = (NN + 255) / 256;         // 391

    k_wprep<<<384, 128, 0, stream>>>(W1, W2, W3, wt);
    hipMemsetAsync(degi, 0, NN * sizeof(int), stream);
    k_degi      <<<(NE + TB - 1) / TB, TB, 0, stream>>>(colv, degi, NE);
    k_blocksum  <<<nScanBlocks, 256, 0, stream>>>(degi, dinv, bsum, NN);
    k_scan_bsum <<<1, 512, 0, stream>>>(bsum, nScanBlocks);
    k_scan_apply<<<nScanBlocks, 256, 0, stream>>>(degi, bsum, rowptr, cursor, NN);
    k_fill_csr  <<<(NE + TB - 1) / TB, TB, 0, stream>>>(row, colv, cursor, csr_off, NE);

    const int gemmBlocks = (NN + 127) / 128;          // 782
    const int aggBlocks  = (NN + 31) / 32;            // 3125

    // layer 1: h16 = dinv*(x@W1) ; a16 = relu(agg(h16)+b1)
    k_gemm<float><<<gemmBlocks, TB, 0, stream>>>(x, wt, dinv, h16, NN);
    k_aggregate<0><<<aggBlocks, TB, 0, stream>>>(h16, csr_off, rowptr, dinv, b1, a16, NN);
    // layer 2: h16 = dinv*(a16@W2) ; a16 = relu(agg(h16)+b2)
    k_gemm<_Float16><<<gemmBlocks, TB, 0, stream>>>(a16, wt + (1 << 14), dinv, h16, NN);
    k_aggregate<0><<<aggBlocks, TB, 0, stream>>>(h16, csr_off, rowptr, dinv, b2, a16, NN);
    // layer 3: h16 = dinv*(a16@W3) ; out = agg(h16) + b3
    k_gemm<_Float16><<<gemmBlocks, TB, 0, stream>>>(a16, wt + (2 << 14), dinv, h16, NN);
    k_aggregate<1><<<aggBlocks, TB, 0, stream>>>(h16, csr_off, rowptr, dinv, b3, out, NN);
}